// Round 9
// baseline (412.006 us; speedup 1.0000x reference)
//
#include <hip/hip_runtime.h>
#include <hip/hip_bf16.h>
#include <math.h>

#define NN 65536
#define MM 32
#define KK 32

#define HALF_LOG_2PI 0.91893853320467274178f
#define L2E 1.44269504088896340736f
#define TTG_EPS 2.2204460492503131e-16f

typedef __attribute__((ext_vector_type(4))) float f32x4;
typedef __attribute__((ext_vector_type(2))) float f32x2;
typedef __attribute__((ext_vector_type(2))) __fp16 fp16x2;  // matches cvt_pkrtz return type

// Accumulate a += v0*2^g0 + v1*2^g1 using the f16 trans pipe.
// Args stay f32-exact; one v_cvt_pkrtz packs the pair to f16 (RTZ, <=2^-11 rel
// err of g -> ~0.1 worst-case log-err over the 32-step chain, vs 0.72 budget).
// v_exp_f16 underflows g<-24 to 0 (harmless: those terms are ~1e-8 relative).
// v_fma_mix_f32 consumes the f16 exp directly into the f32 accumulator (no
// cvt back). s_nop 0 covers the trans->consumer wait state the compiler can't
// see through the asm boundary.
static __device__ __forceinline__ float acc2_f16(float a, float g0, float g1,
                                                 float v0, float v1) {
  fp16x2 h = __builtin_amdgcn_cvt_pkrtz(g0, g1);
  unsigned int hb = __builtin_bit_cast(unsigned int, h);
  unsigned int hh = hb >> 16;
  unsigned int e0, e1;
  asm("v_exp_f16 %0, %1\n\ts_nop 0" : "=v"(e0) : "v"(hb));
  asm("v_exp_f16 %0, %1\n\ts_nop 0" : "=v"(e1) : "v"(hh));
  asm("v_fma_mix_f32 %0, %1, %2, %0 op_sel_hi:[1,0,0]" : "+v"(a) : "v"(e0), "v"(v0));
  asm("v_fma_mix_f32 %0, %1, %2, %0 op_sel_hi:[1,0,0]" : "+v"(a) : "v"(e1), "v"(v1));
  return a;
}

// ws layout (floats):
//   [0..31]   softmax(wk0)
//   [64 ...]  params as float4, plane layout:
//             float4 index = ((i*3 + p)*8 + jq)*32 + k,  component = j&3  (j = jq*4 + jc)
//             p: 0=P0, 1=P1, 2=P2.  exp2-argument = P0 + P1*x + P2*x^2.
__global__ void ttg_precompute(const float* __restrict__ wk0_logits,
                               const float* __restrict__ W_logits,
                               const float* __restrict__ mu,
                               const float* __restrict__ pre_sigma,
                               float* __restrict__ ws) {
  int i = blockIdx.x;  // 0..31
  __shared__ float wsl[1024];
  __shared__ float lse[32];
  for (int t = threadIdx.x; t < 1024; t += blockDim.x)
    wsl[t] = W_logits[i * 1024 + t];
  __syncthreads();
  if (threadIdx.x < 32) {
    int j = threadIdx.x;
    float mx = -1e30f;
    for (int k = 0; k < 32; ++k) mx = fmaxf(mx, wsl[k * 32 + j]);
    float s = 0.f;
    for (int k = 0; k < 32; ++k) s += expf(wsl[k * 32 + j] - mx);
    lse[j] = mx + logf(s);
  }
  __syncthreads();
  float* params = ws + 64;
  for (int t = threadIdx.x; t < 1024; t += blockDim.x) {
    int k = t >> 5, j = t & 31;
    float ps = pre_sigma[t];
    float sg = log1pf(expf(-fabsf(ps))) + fmaxf(ps, 0.f);  // softplus
    float a = 1.f / sg;
    float b = mu[t] * a;
    float lw = wsl[t] - lse[j];
    float c = lw - logf(sg) - HALF_LOG_2PI;
    float P0 = (c - 0.5f * b * b) * L2E;
    float P1 = (a * b) * L2E;
    float P2 = (-0.5f * a * a) * L2E;
    int jq = j >> 2, jc = j & 3;
    params[((((i * 3 + 0) * 8 + jq) * 32) + k) * 4 + jc] = P0;
    params[((((i * 3 + 1) * 8 + jq) * 32) + k) * 4 + jc] = P1;
    params[((((i * 3 + 2) * 8 + jq) * 32) + k) * 4 + jc] = P2;
  }
  if (i == 0 && threadIdx.x < 32) {
    float mx = -1e30f;
    for (int j = 0; j < 32; ++j) mx = fmaxf(mx, wk0_logits[j]);
    float s = 0.f;
    for (int j = 0; j < 32; ++j) s += expf(wk0_logits[j] - mx);
    ws[threadIdx.x] = expf(wk0_logits[threadIdx.x] - mx) / s;
  }
}

// 256 threads = 4 independent waves, no __syncthreads in the main loop.
// Lane L: k = L&31 (output row), sh = L>>5. Wave owns 16 samples; per pair-slot
// tt the two half-waves process samples 2tt and 2tt+1.
// Structure identical to the 321us round-4 kernel; only the exp+acc changed
// (f16 trans-pipe probe).
__global__ __launch_bounds__(256, 4) void ttg_main(const float* __restrict__ X,
                                                   const float* __restrict__ ws,
                                                   float* __restrict__ out) {
  __shared__ __align__(16) float vbuf[4][16][32];    // [wave][sample][k]  8 KB
  __shared__ __align__(8)  f32x2 xbuf[4][16][32];    // [wave][sample][i] = (x, x^2)  16 KB
  const int t = threadIdx.x;
  const int wv = t >> 6;
  const int L = t & 63;
  const int k = L & 31;
  const int sh = L >> 5;
  const int n0 = (blockIdx.x * 4 + wv) * 16;

  // stage x (+x^2), fully coalesced
  for (int r = 0; r < 8; ++r) {
    int f = L + 64 * r;  // 0..511
    int s = f >> 5, i = f & 31;
    float x = X[n0 * 32 + f];
    xbuf[wv][s][i] = (f32x2){x, x * x};
  }
  // init v = softmax(wk0)
  {
    float w0 = ws[k];
#pragma unroll
    for (int rep = 0; rep < 8; ++rep)
      vbuf[wv][rep * 2 + sh][k] = w0;
  }

  const f32x4* __restrict__ P = (const f32x4*)(ws + 64);

  for (int i = 0; i < 32; ++i) {
    const f32x4* Pi = P + i * 768 + k;
    f32x4 q0[4], q1[4], q2[4];
    float acc[8];

    // ---- half A: j-quads 0..3 ----
#pragma unroll
    for (int jq = 0; jq < 4; ++jq) {
      q0[jq] = Pi[jq * 32];
      q1[jq] = Pi[256 + jq * 32];
      q2[jq] = Pi[512 + jq * 32];
    }
#pragma unroll
    for (int tt = 0; tt < 8; ++tt) {
      const int s = tt * 2 + sh;
      f32x2 xx = xbuf[wv][s][i];
      float a = 0.f;
#pragma unroll
      for (int jq = 0; jq < 4; ++jq) {
        f32x4 v4 = *(const f32x4*)&vbuf[wv][s][jq * 4];  // broadcast b128
        float g0 = fmaf(q2[jq].x, xx.y, fmaf(q1[jq].x, xx.x, q0[jq].x));
        float g1 = fmaf(q2[jq].y, xx.y, fmaf(q1[jq].y, xx.x, q0[jq].y));
        float g2 = fmaf(q2[jq].z, xx.y, fmaf(q1[jq].z, xx.x, q0[jq].z));
        float g3 = fmaf(q2[jq].w, xx.y, fmaf(q1[jq].w, xx.x, q0[jq].w));
        a = acc2_f16(a, g0, g1, v4.x, v4.y);
        a = acc2_f16(a, g2, g3, v4.z, v4.w);
      }
      acc[tt] = a;
    }

    // ---- half B: j-quads 4..7 ----
#pragma unroll
    for (int jq = 0; jq < 4; ++jq) {
      q0[jq] = Pi[(jq + 4) * 32];
      q1[jq] = Pi[256 + (jq + 4) * 32];
      q2[jq] = Pi[512 + (jq + 4) * 32];
    }
#pragma unroll
    for (int tt = 0; tt < 8; ++tt) {
      const int s = tt * 2 + sh;
      f32x2 xx = xbuf[wv][s][i];
      float a = acc[tt];
#pragma unroll
      for (int jq = 0; jq < 4; ++jq) {
        f32x4 v4 = *(const f32x4*)&vbuf[wv][s][(jq + 4) * 4];
        float g0 = fmaf(q2[jq].x, xx.y, fmaf(q1[jq].x, xx.x, q0[jq].x));
        float g1 = fmaf(q2[jq].y, xx.y, fmaf(q1[jq].y, xx.x, q0[jq].y));
        float g2 = fmaf(q2[jq].z, xx.y, fmaf(q1[jq].z, xx.x, q0[jq].z));
        float g3 = fmaf(q2[jq].w, xx.y, fmaf(q1[jq].w, xx.x, q0[jq].w));
        a = acc2_f16(a, g0, g1, v4.x, v4.y);
        a = acc2_f16(a, g2, g3, v4.z, v4.w);
      }
      acc[tt] = a;
    }

    if (i < 31) {
      // publish new v; all reads of step i precede these writes in wave
      // program order, and step i+1's reads follow them (in-order DS pipe).
#pragma unroll
      for (int tt = 0; tt < 8; ++tt)
        vbuf[wv][tt * 2 + sh][k] = acc[tt];
    } else {
      // final step: reduce over k within each half-wave and emit
#pragma unroll
      for (int tt = 0; tt < 8; ++tt) {
        float val = acc[tt];
        val += __shfl_xor(val, 1);
        val += __shfl_xor(val, 2);
        val += __shfl_xor(val, 4);
        val += __shfl_xor(val, 8);
        val += __shfl_xor(val, 16);
        if (k == 0) out[n0 + tt * 2 + sh] = logf(val + TTG_EPS);
      }
    }
  }
}

extern "C" void kernel_launch(void* const* d_in, const int* in_sizes, int n_in,
                              void* d_out, int out_size, void* d_ws, size_t ws_size,
                              hipStream_t stream) {
  const float* X          = (const float*)d_in[0];
  const float* wk0_logits = (const float*)d_in[1];
  const float* W_logits   = (const float*)d_in[2];
  const float* mu         = (const float*)d_in[3];
  const float* pre_sigma  = (const float*)d_in[4];
  float* out = (float*)d_out;
  float* ws  = (float*)d_ws;

  ttg_precompute<<<32, 256, 0, stream>>>(wk0_logits, W_logits, mu, pre_sigma, ws);
  ttg_main<<<1024, 256, 0, stream>>>(X, ws, out);
}

// Round 10
// 359.676 us; speedup vs baseline: 1.1455x; 1.1455x over previous
//
#include <hip/hip_runtime.h>
#include <hip/hip_bf16.h>
#include <math.h>

#define NN 65536
#define MM 32
#define KK 32

#define HALF_LOG_2PI 0.91893853320467274178f
#define L2E 1.44269504088896340736f
#define TTG_EPS 2.2204460492503131e-16f

typedef __attribute__((ext_vector_type(4))) float f32x4;
typedef __attribute__((ext_vector_type(2))) float f32x2;
typedef __attribute__((ext_vector_type(2))) __fp16 fp16x2;

static __device__ __forceinline__ float fast_exp2(float x) {
#if __has_builtin(__builtin_amdgcn_exp2f)
  return __builtin_amdgcn_exp2f(x);
#else
  float r;
  asm("v_exp_f32 %0, %1\n\ts_nop 1" : "=v"(r) : "v"(x));
  return r;
#endif
}

// g = P1*x + P2*x^2 + P0 in ONE full-rate VOP3P: v_dot2_f32_f16.
// pk holds (P1,P2) as f16 pair; xh holds (x,x^2) as f16 pair; c = P0 (f32).
// f16 products accumulate in f32 — only input quantization (2^-11 rel) matters;
// round-9's full-g-in-f16 probe (same error scale) passed with absmax ~0.
static __device__ __forceinline__ float arg_dot2(float pk, unsigned int xh, float c) {
#if __has_builtin(__builtin_amdgcn_fdot2)
  return __builtin_amdgcn_fdot2(__builtin_bit_cast(fp16x2, pk),
                                __builtin_bit_cast(fp16x2, xh), c, false);
#else
  float r;
  asm("v_dot2_f32_f16 %0, %1, %2, %3" : "=v"(r) : "v"(pk), "v"(xh), "v"(c));
  return r;
#endif
}

// ws layout (floats):
//   [0..31]   softmax(wk0)
//   [64 ...]  params as float4, plane layout:
//             f32x4 index = ((i*2 + p)*8 + jq)*32 + k, component = j&3
//             p=0: P0 (f32).  p=1: packed f16 pair (P1,P2) bitcast to f32.
//             exp2-argument = P0 + P1*x + P2*x^2.
__global__ void ttg_precompute(const float* __restrict__ wk0_logits,
                               const float* __restrict__ W_logits,
                               const float* __restrict__ mu,
                               const float* __restrict__ pre_sigma,
                               float* __restrict__ ws) {
  int i = blockIdx.x;  // 0..31
  __shared__ float wsl[1024];
  __shared__ float lse[32];
  for (int t = threadIdx.x; t < 1024; t += blockDim.x)
    wsl[t] = W_logits[i * 1024 + t];
  __syncthreads();
  if (threadIdx.x < 32) {
    int j = threadIdx.x;
    float mx = -1e30f;
    for (int k = 0; k < 32; ++k) mx = fmaxf(mx, wsl[k * 32 + j]);
    float s = 0.f;
    for (int k = 0; k < 32; ++k) s += expf(wsl[k * 32 + j] - mx);
    lse[j] = mx + logf(s);
  }
  __syncthreads();
  float* params = ws + 64;
  for (int t = threadIdx.x; t < 1024; t += blockDim.x) {
    int k = t >> 5, j = t & 31;
    float ps = pre_sigma[t];
    float sg = log1pf(expf(-fabsf(ps))) + fmaxf(ps, 0.f);  // softplus
    float a = 1.f / sg;
    float b = mu[t] * a;
    float lw = wsl[t] - lse[j];
    float c = lw - logf(sg) - HALF_LOG_2PI;
    float P0 = (c - 0.5f * b * b) * L2E;
    float P1 = (a * b) * L2E;
    float P2 = (-0.5f * a * a) * L2E;
    int jq = j >> 2, jc = j & 3;
    fp16x2 pk = __builtin_amdgcn_cvt_pkrtz(P1, P2);
    params[(((i * 2 + 0) * 8 + jq) * 32 + k) * 4 + jc] = P0;
    params[(((i * 2 + 1) * 8 + jq) * 32 + k) * 4 + jc] = __builtin_bit_cast(float, pk);
  }
  if (i == 0 && threadIdx.x < 32) {
    float mx = -1e30f;
    for (int j = 0; j < 32; ++j) mx = fmaxf(mx, wk0_logits[j]);
    float s = 0.f;
    for (int j = 0; j < 32; ++j) s += expf(wk0_logits[j] - mx);
    ws[threadIdx.x] = expf(wk0_logits[threadIdx.x] - mx) / s;
  }
}

// 256 threads = 4 independent waves, no __syncthreads in the main loop.
// Lane L: k = L&31 (output row), sh = L>>5. Wave owns 16 samples; per pair-slot
// tt the two half-waves process samples 2tt and 2tt+1.
// Structure identical to the 321us round-4 kernel; arg FMAs replaced by one
// v_dot2_f32_f16 (port cost 22 -> 20 cyc/elem).
__global__ __launch_bounds__(256, 4) void ttg_main(const float* __restrict__ X,
                                                   const float* __restrict__ ws,
                                                   float* __restrict__ out) {
  __shared__ __align__(16) float vbuf[4][16][32];       // [wave][sample][k]  8 KB
  __shared__ unsigned int xbuf[4][16][32];              // [wave][sample][i] = pk(x,x^2)  8 KB
  const int t = threadIdx.x;
  const int wv = t >> 6;
  const int L = t & 63;
  const int k = L & 31;
  const int sh = L >> 5;
  const int n0 = (blockIdx.x * 4 + wv) * 16;

  // stage pk(x, x^2), fully coalesced
  for (int r = 0; r < 8; ++r) {
    int f = L + 64 * r;  // 0..511
    int s = f >> 5, i = f & 31;
    float x = X[n0 * 32 + f];
    fp16x2 xp = __builtin_amdgcn_cvt_pkrtz(x, x * x);
    xbuf[wv][s][i] = __builtin_bit_cast(unsigned int, xp);
  }
  // init v = softmax(wk0)
  {
    float w0 = ws[k];
#pragma unroll
    for (int rep = 0; rep < 8; ++rep)
      vbuf[wv][rep * 2 + sh][k] = w0;
  }

  const f32x4* __restrict__ P = (const f32x4*)(ws + 64);

  for (int i = 0; i < 32; ++i) {
    const f32x4* Pi = P + i * 512 + k;
    f32x4 q0[4], qk[4];
    float acc[8];

    // ---- half A: j-quads 0..3 ----
#pragma unroll
    for (int jq = 0; jq < 4; ++jq) {
      q0[jq] = Pi[jq * 32];          // P0 x4
      qk[jq] = Pi[256 + jq * 32];    // pk(P1,P2) x4
    }
#pragma unroll
    for (int tt = 0; tt < 8; ++tt) {
      const int s = tt * 2 + sh;
      unsigned int xh = xbuf[wv][s][i];
      float a = 0.f;
#pragma unroll
      for (int jq = 0; jq < 4; ++jq) {
        f32x4 v4 = *(const f32x4*)&vbuf[wv][s][jq * 4];  // broadcast b128
        a = fmaf(v4.x, fast_exp2(arg_dot2(qk[jq].x, xh, q0[jq].x)), a);
        a = fmaf(v4.y, fast_exp2(arg_dot2(qk[jq].y, xh, q0[jq].y)), a);
        a = fmaf(v4.z, fast_exp2(arg_dot2(qk[jq].z, xh, q0[jq].z)), a);
        a = fmaf(v4.w, fast_exp2(arg_dot2(qk[jq].w, xh, q0[jq].w)), a);
      }
      acc[tt] = a;
    }

    // ---- half B: j-quads 4..7 ----
#pragma unroll
    for (int jq = 0; jq < 4; ++jq) {
      q0[jq] = Pi[(jq + 4) * 32];
      qk[jq] = Pi[256 + (jq + 4) * 32];
    }
#pragma unroll
    for (int tt = 0; tt < 8; ++tt) {
      const int s = tt * 2 + sh;
      unsigned int xh = xbuf[wv][s][i];
      float a = acc[tt];
#pragma unroll
      for (int jq = 0; jq < 4; ++jq) {
        f32x4 v4 = *(const f32x4*)&vbuf[wv][s][(jq + 4) * 4];
        a = fmaf(v4.x, fast_exp2(arg_dot2(qk[jq].x, xh, q0[jq].x)), a);
        a = fmaf(v4.y, fast_exp2(arg_dot2(qk[jq].y, xh, q0[jq].y)), a);
        a = fmaf(v4.z, fast_exp2(arg_dot2(qk[jq].z, xh, q0[jq].z)), a);
        a = fmaf(v4.w, fast_exp2(arg_dot2(qk[jq].w, xh, q0[jq].w)), a);
      }
      acc[tt] = a;
    }

    if (i < 31) {
      // publish new v; all reads of step i precede these writes in wave
      // program order, and step i+1's reads follow them (in-order DS pipe).
#pragma unroll
      for (int tt = 0; tt < 8; ++tt)
        vbuf[wv][tt * 2 + sh][k] = acc[tt];
    } else {
      // final step: reduce over k within each half-wave and emit
#pragma unroll
      for (int tt = 0; tt < 8; ++tt) {
        float val = acc[tt];
        val += __shfl_xor(val, 1);
        val += __shfl_xor(val, 2);
        val += __shfl_xor(val, 4);
        val += __shfl_xor(val, 8);
        val += __shfl_xor(val, 16);
        if (k == 0) out[n0 + tt * 2 + sh] = logf(val + TTG_EPS);
      }
    }
  }
}

extern "C" void kernel_launch(void* const* d_in, const int* in_sizes, int n_in,
                              void* d_out, int out_size, void* d_ws, size_t ws_size,
                              hipStream_t stream) {
  const float* X          = (const float*)d_in[0];
  const float* wk0_logits = (const float*)d_in[1];
  const float* W_logits   = (const float*)d_in[2];
  const float* mu         = (const float*)d_in[3];
  const float* pre_sigma  = (const float*)d_in[4];
  float* out = (float*)d_out;
  float* ws  = (float*)d_ws;

  ttg_precompute<<<32, 256, 0, stream>>>(wk0_logits, W_logits, mu, pre_sigma, ws);
  ttg_main<<<1024, 256, 0, stream>>>(X, ws, out);
}